// Round 4
// baseline (2713.120 us; speedup 1.0000x reference)
//
#include <hip/hip_runtime.h>
#include <cstdint>
#include <cstddef>

#define NDIM 8192
#define NITER 20
#define NBLK 256      // blocks for k_first/k_iter (1 per CU)
#define CHUNKS 4      // 8-row chunks per block
#define ROWS 8        // rows per chunk; block covers CHUNKS*ROWS = 32 rows

// ---------- helpers ----------
__device__ __forceinline__ unsigned short f2bf_rne(float f) {
  unsigned int u = __float_as_uint(f);
  unsigned int r = 0x7fffu + ((u >> 16) & 1u);
  return (unsigned short)((u + r) >> 16);
}
__device__ __forceinline__ unsigned int pack2(float lo, float hi) {
  return (unsigned int)f2bf_rne(lo) | ((unsigned int)f2bf_rne(hi) << 16);
}
__device__ __forceinline__ float bflo(unsigned int u) { return __uint_as_float(u << 16); }
__device__ __forceinline__ float bfhi(unsigned int u) { return __uint_as_float(u & 0xffff0000u); }

// Block-wide reduction over 1024 threads for 8 rows. 2 barriers.
// Writes 1/rowsum into ash[0..7] and a_out[i0..i0+7].
__device__ __forceinline__ void rows8_reduce(float (&dots)[8], float* ash,
                                             float* __restrict__ a_out, int i0) {
  const int t = threadIdx.x;
#pragma unroll
  for (int r = 0; r < 8; ++r)
#pragma unroll
    for (int m = 32; m >= 1; m >>= 1)
      dots[r] += __shfl_xor(dots[r], m, 64);
  __shared__ float red[16][8];
  const int w = t >> 6;
  if ((t & 63) == 0) {
#pragma unroll
    for (int r = 0; r < 8; ++r) red[w][r] = dots[r];
  }
  __syncthreads();
  if (t < 8) {
    float s = 0.0f;
#pragma unroll
    for (int ww = 0; ww < 16; ++ww) s += red[ww][t];
    float inv = 1.0f / s;
    ash[t] = inv;
    a_out[i0 + t] = inv;
  }
  __syncthreads();
}

// ---------- kernels ----------

// Iteration 1 fused with exp: reads H, writes E=bf16(exp(H)), computes
// a = 1/rowsum (b==1) and accumulated column partials for its 32 rows.
__global__ __launch_bounds__(1024) void k_first(const float* __restrict__ H,
                                                unsigned short* __restrict__ E,
                                                float* __restrict__ a,
                                                float* __restrict__ partial) {
  const int t = threadIdx.x;
  const int j0 = t * 8;
  const int blk = blockIdx.x;
  __shared__ float ash[8];

  float cs[8];
#pragma unroll
  for (int k = 0; k < 8; ++k) cs[k] = 0.0f;

#pragma unroll 1
  for (int c = 0; c < CHUNKS; ++c) {
    const int i0 = blk * (CHUNKS * ROWS) + c * ROWS;
    uint4 cur[8];
    float dots[8];
#pragma unroll
    for (int r = 0; r < 8; ++r) {
      const float* hp = H + (size_t)(i0 + r) * NDIM + j0;
      float4 h0 = reinterpret_cast<const float4*>(hp)[0];
      float4 h1 = reinterpret_cast<const float4*>(hp)[1];
      float e0 = __expf(h0.x), e1 = __expf(h0.y), e2 = __expf(h0.z), e3 = __expf(h0.w);
      float e4 = __expf(h1.x), e5 = __expf(h1.y), e6 = __expf(h1.z), e7 = __expf(h1.w);
      cur[r] = uint4{pack2(e0, e1), pack2(e2, e3), pack2(e4, e5), pack2(e6, e7)};
      *reinterpret_cast<uint4*>(E + (size_t)(i0 + r) * NDIM + j0) = cur[r];
      dots[r] = ((e0 + e1) + (e2 + e3)) + ((e4 + e5) + (e6 + e7));
    }
    rows8_reduce(dots, ash, a, i0);
#pragma unroll
    for (int r = 0; r < 8; ++r) {
      const float ai = ash[r];
      cs[0] += ai * bflo(cur[r].x); cs[1] += ai * bfhi(cur[r].x);
      cs[2] += ai * bflo(cur[r].y); cs[3] += ai * bfhi(cur[r].y);
      cs[4] += ai * bflo(cur[r].z); cs[5] += ai * bfhi(cur[r].z);
      cs[6] += ai * bflo(cur[r].w); cs[7] += ai * bfhi(cur[r].w);
    }
  }
  float4* pp = reinterpret_cast<float4*>(partial + (size_t)blk * NDIM + j0);
  pp[0] = float4{cs[0], cs[1], cs[2], cs[3]};
  pp[1] = float4{cs[4], cs[5], cs[6], cs[7]};
}

// Generic iteration: one pass over E. Block owns 32 full rows (4 chunks of 8),
// packed-bf16 registers with next-chunk prefetch; one partial row per block.
__global__ __launch_bounds__(1024) void k_iter(const unsigned short* __restrict__ E,
                                               const float* __restrict__ b,
                                               float* __restrict__ a,
                                               float* __restrict__ partial) {
  const int t = threadIdx.x;
  const int j0 = t * 8;
  const int blk = blockIdx.x;
  __shared__ float ash[8];

  const float4* bp = reinterpret_cast<const float4*>(b + j0);
  float4 b0 = bp[0], b1 = bp[1];
  float breg[8] = {b0.x, b0.y, b0.z, b0.w, b1.x, b1.y, b1.z, b1.w};

  float cs[8];
#pragma unroll
  for (int k = 0; k < 8; ++k) cs[k] = 0.0f;

  const unsigned short* Eb = E + (size_t)blk * (CHUNKS * ROWS) * NDIM;
  uint4 cur[8], nxt[8];
#pragma unroll
  for (int r = 0; r < 8; ++r)
    cur[r] = *reinterpret_cast<const uint4*>(Eb + (size_t)r * NDIM + j0);

#pragma unroll
  for (int c = 0; c < CHUNKS; ++c) {
    if (c + 1 < CHUNKS) {
#pragma unroll
      for (int r = 0; r < 8; ++r)
        nxt[r] = *reinterpret_cast<const uint4*>(Eb + (size_t)((c + 1) * ROWS + r) * NDIM + j0);
    }
    float dots[8];
#pragma unroll
    for (int r = 0; r < 8; ++r) {
      dots[r] = ((bflo(cur[r].x) * breg[0] + bfhi(cur[r].x) * breg[1]) +
                 (bflo(cur[r].y) * breg[2] + bfhi(cur[r].y) * breg[3])) +
                ((bflo(cur[r].z) * breg[4] + bfhi(cur[r].z) * breg[5]) +
                 (bflo(cur[r].w) * breg[6] + bfhi(cur[r].w) * breg[7]));
    }
    rows8_reduce(dots, ash, a, blk * (CHUNKS * ROWS) + c * ROWS);
#pragma unroll
    for (int r = 0; r < 8; ++r) {
      const float ai = ash[r];
      cs[0] += ai * bflo(cur[r].x); cs[1] += ai * bfhi(cur[r].x);
      cs[2] += ai * bflo(cur[r].y); cs[3] += ai * bfhi(cur[r].y);
      cs[4] += ai * bflo(cur[r].z); cs[5] += ai * bfhi(cur[r].z);
      cs[6] += ai * bflo(cur[r].w); cs[7] += ai * bfhi(cur[r].w);
    }
#pragma unroll
    for (int r = 0; r < 8; ++r) cur[r] = nxt[r];
  }
  float4* pp = reinterpret_cast<float4*>(partial + (size_t)blk * NDIM + j0);
  pp[0] = float4{cs[0], cs[1], cs[2], cs[3]};
  pp[1] = float4{cs[4], cs[5], cs[6], cs[7]};
}

// b[j] = 1 / sum_{p<256} partial[p][j]
__global__ void k_colreduce(const float* __restrict__ partial, float* __restrict__ b) {
  const int j = blockIdx.x * blockDim.x + threadIdx.x;   // 64 blocks x 128 threads
  float s0 = 0.0f, s1 = 0.0f, s2 = 0.0f, s3 = 0.0f;
#pragma unroll 4
  for (int p = 0; p < NBLK; p += 4) {
    s0 += partial[(size_t)(p + 0) * NDIM + j];
    s1 += partial[(size_t)(p + 1) * NDIM + j];
    s2 += partial[(size_t)(p + 2) * NDIM + j];
    s3 += partial[(size_t)(p + 3) * NDIM + j];
  }
  b[j] = 1.0f / ((s0 + s1) + (s2 + s3));
}

// out[i][j] = exp(H[i][j]) * a[i] * b[j]  (fp32; overwrites E/partial — dead)
__global__ void k_final(const float* __restrict__ H,
                        const float* __restrict__ a,
                        const float* __restrict__ b,
                        float* __restrict__ out) {
  const size_t nv = (size_t)NDIM * NDIM / 4;
  const size_t stride = (size_t)gridDim.x * blockDim.x;
  for (size_t v = (size_t)blockIdx.x * blockDim.x + threadIdx.x; v < nv; v += stride) {
    float4 h = reinterpret_cast<const float4*>(H)[v];
    const int i = (int)(v >> 11);
    const int jv = (int)(v & 2047);
    float4 bb = reinterpret_cast<const float4*>(b)[jv];
    const float ai = a[i];
    float4 o;
    o.x = __expf(h.x) * ai * bb.x;
    o.y = __expf(h.y) * ai * bb.y;
    o.z = __expf(h.z) * ai * bb.z;
    o.w = __expf(h.w) * ai * bb.w;
    reinterpret_cast<float4*>(out)[v] = o;
  }
}

// ---------- launch ----------
extern "C" void kernel_launch(void* const* d_in, const int* in_sizes, int n_in,
                              void* d_out, int out_size, void* d_ws, size_t ws_size,
                              hipStream_t stream) {
  const float* H = (const float*)d_in[0];
  float* out = (float*)d_out;
  unsigned short* E = (unsigned short*)d_out;                          // 128MB bf16
  float* partial = (float*)((char*)d_out + (size_t)NDIM * NDIM * 2);   // 8MB (NBLK x NDIM)
  float* a = (float*)d_ws;                                             // [NDIM]
  float* b = a + NDIM;                                                 // [NDIM]

  // iteration 1 (b == 1), fused with exp
  k_first<<<NBLK, 1024, 0, stream>>>(H, E, a, partial);
  k_colreduce<<<NDIM / 128, 128, 0, stream>>>(partial, b);

  // iterations 2..20
  for (int it = 1; it < NITER; ++it) {
    k_iter<<<NBLK, 1024, 0, stream>>>(E, b, a, partial);
    k_colreduce<<<NDIM / 128, 128, 0, stream>>>(partial, b);
  }

  k_final<<<2048, 256, 0, stream>>>(H, a, b, out);
}